// Round 1
// baseline (44.318 us; speedup 1.0000x reference)
//
#include <hip/hip_runtime.h>

// Problem constants (from reference): A (256, 512, 2) f32, B (2, 1024) f32,
// out (256, 1) f32.
constexpr int BATCH  = 256;
constexpr int MAXLEN = 512;
constexpr int LENF   = 1024;

// out[b] = bump( max_c min_l min(q(l,c), q(l,c+512)) ),
//   q(l,f) = max(|A[b,l,0]-B[0,f]|, |A[b,l,1]-B[1,f]|)   (Chebyshev distance)
//   bump(t) = e/(1+e)^2, e = exp(-10 t)   (== sigmoid(10t)*sigmoid(-10t), t>=0)
__global__ __launch_bounds__(512)
void bump_minmax_kernel(const float* __restrict__ A,
                        const float* __restrict__ B,
                        float* __restrict__ out)
{
    const int b = blockIdx.x;
    const int c = threadIdx.x;  // one c per thread, c in [0, 512)

    __shared__ float sA[MAXLEN * 2];  // A[b] tile: 4 KB
    __shared__ float sred[8];         // per-wave partial maxima

    // Stage A[b] into LDS: 1024 floats = 256 float4, coalesced.
    const float4* Asrc = reinterpret_cast<const float4*>(A + (size_t)b * MAXLEN * 2);
    if (c < (MAXLEN * 2) / 4) {
        reinterpret_cast<float4*>(sA)[c] = Asrc[c];
    }

    // This thread's two B columns (f = c and f = c + 512).
    const float b0c = B[c];
    const float b1c = B[LENF + c];
    const float b0d = B[c + MAXLEN];
    const float b1d = B[LENF + c + MAXLEN];

    __syncthreads();

    float rmin = 3.4e38f;
#pragma unroll 8
    for (int l = 0; l < MAXLEN; ++l) {
        const float a0 = sA[2 * l];      // broadcast read — conflict-free
        const float a1 = sA[2 * l + 1];
        const float q1 = fmaxf(fabsf(a0 - b0c), fabsf(a1 - b1c));
        const float q2 = fmaxf(fabsf(a0 - b0d), fabsf(a1 - b1d));
        rmin = fminf(rmin, fminf(q1, q2));
    }

    // Block-wide max over the 512 c values.
    float v = rmin;
#pragma unroll
    for (int off = 32; off > 0; off >>= 1)
        v = fmaxf(v, __shfl_xor(v, off));   // 64-lane wave butterfly
    const int lane = c & 63;
    const int wid  = c >> 6;
    if (lane == 0) sred[wid] = v;
    __syncthreads();

    if (c == 0) {
        float t = sred[0];
#pragma unroll
        for (int i = 1; i < 8; ++i) t = fmaxf(t, sred[i]);
        const float e = expf(-10.0f * t);   // t >= 0, e <= 1: stable
        const float d = 1.0f + e;
        out[b] = e / (d * d);               // sigmoid(10t)*sigmoid(-10t)
    }
}

extern "C" void kernel_launch(void* const* d_in, const int* in_sizes, int n_in,
                              void* d_out, int out_size, void* d_ws, size_t ws_size,
                              hipStream_t stream)
{
    const float* A = (const float*)d_in[0];   // (256, 512, 2) f32
    const float* B = (const float*)d_in[1];   // (2, 1024) f32
    float* out = (float*)d_out;               // (256, 1) f32

    hipLaunchKernelGGL(bump_minmax_kernel, dim3(BATCH), dim3(512), 0, stream,
                       A, B, out);
}

// Round 2
// 23.091 us; speedup vs baseline: 1.9193x; 1.9193x over previous
//
#include <hip/hip_runtime.h>

// A (256, 512, 2) f32, B (2, 1024) f32, out (256, 1) f32.
constexpr int BATCH  = 256;
constexpr int MAXLEN = 512;
constexpr int LENF   = 1024;

// Math (verified absmax==0 in R1):
//   out[b] = bump( max_c min( u(b,c), u(b,c+512) ) ),  c in [0,512)
//   u(b,f) = min_l max(|A[b,l,0]-B[0,f]|, |A[b,l,1]-B[1,f]|)
//   bump(t) = e/(1+e)^2, e = exp(-10 t)
//
// Kernel 1: 1024 blocks (4 per batch) x 256 threads. Each thread owns one
// f column, computes u(b,f) over all 512 l with 4 independent min chains,
// block pairs the two columns of each c, max-reduces its 128 c's, and
// atomicMax's the uint bits (values >= 0 -> monotone) into ws[b].
__global__ __launch_bounds__(256)
void chebmin_kernel(const float* __restrict__ A,
                    const float* __restrict__ B,
                    unsigned* __restrict__ tmax)
{
    const int bid = blockIdx.x;
    const int b   = bid >> 2;
    const int s   = bid & 3;
    const int t   = threadIdx.x;
    const int cl  = t & 127;        // local c index within this block
    const int col = t >> 7;         // 0: f=c, 1: f=c+512
    const int c   = s * 128 + cl;   // global c in [0,512)
    const int f   = c + col * MAXLEN;

    __shared__ float sA[MAXLEN * 2];   // A[b]: 4 KB
    __shared__ float su[256];
    __shared__ float sw[2];

    // Stage A[b]: 256 threads x float4 = 4 KB, coalesced.
    reinterpret_cast<float4*>(sA)[t] =
        reinterpret_cast<const float4*>(A + (size_t)b * MAXLEN * 2)[t];

    const float b0 = B[f];
    const float b1 = B[LENF + f];

    __syncthreads();

    // 4 independent min chains over l (break the serial v_min spine).
    float u0 = 3.4e38f, u1 = 3.4e38f, u2 = 3.4e38f, u3 = 3.4e38f;
#pragma unroll 4
    for (int l = 0; l < MAXLEN; l += 4) {
        const float4 p = reinterpret_cast<const float4*>(sA)[(l >> 1)];     // a(l), a(l+1)
        const float4 q = reinterpret_cast<const float4*>(sA)[(l >> 1) + 1]; // a(l+2), a(l+3)
        u0 = fminf(u0, fmaxf(fabsf(p.x - b0), fabsf(p.y - b1)));
        u1 = fminf(u1, fmaxf(fabsf(p.z - b0), fabsf(p.w - b1)));
        u2 = fminf(u2, fmaxf(fabsf(q.x - b0), fabsf(q.y - b1)));
        u3 = fminf(u3, fmaxf(fabsf(q.z - b0), fabsf(q.w - b1)));
    }
    const float u = fminf(fminf(u0, u1), fminf(u2, u3));

    // Pair the two columns of each c, then max over this block's 128 c's.
    su[t] = u;
    __syncthreads();
    if (t < 128) {
        float v = fminf(su[t], su[t + 128]);   // min over coord-pair for c
#pragma unroll
        for (int off = 32; off > 0; off >>= 1)
            v = fmaxf(v, __shfl_xor(v, off));  // 64-lane wave max
        if ((t & 63) == 0) sw[t >> 6] = v;
    }
    __syncthreads();
    if (t == 0) {
        const float m = fmaxf(sw[0], sw[1]);
        atomicMax(tmax + b, __float_as_uint(m));  // m >= 0: bits are monotone
    }
}

// Kernel 2: apply the bump to the 256 per-batch maxima.
__global__ __launch_bounds__(256)
void bump_kernel(const unsigned* __restrict__ tmax, float* __restrict__ out)
{
    const int b = threadIdx.x;
    const float tv = __uint_as_float(tmax[b]);
    const float e  = expf(-10.0f * tv);   // tv >= 0, e <= 1: stable
    const float d  = 1.0f + e;
    out[b] = e / (d * d);
}

extern "C" void kernel_launch(void* const* d_in, const int* in_sizes, int n_in,
                              void* d_out, int out_size, void* d_ws, size_t ws_size,
                              hipStream_t stream)
{
    const float* A = (const float*)d_in[0];
    const float* B = (const float*)d_in[1];
    float* out = (float*)d_out;
    unsigned* tmax = (unsigned*)d_ws;    // 256 x u32 = 1 KB of scratch

    hipMemsetAsync(tmax, 0, BATCH * sizeof(unsigned), stream);
    hipLaunchKernelGGL(chebmin_kernel, dim3(BATCH * 4), dim3(256), 0, stream,
                       A, B, tmax);
    hipLaunchKernelGGL(bump_kernel, dim3(1), dim3(256), 0, stream, tmax, out);
}

// Round 3
// 19.414 us; speedup vs baseline: 2.2828x; 1.1894x over previous
//
#include <hip/hip_runtime.h>

// A (256, 512, 2) f32, B (2, 1024) f32, out (256, 1) f32.
constexpr int BATCH  = 256;
constexpr int MAXLEN = 512;
constexpr int LENF   = 1024;

// out[b] = bump( max_c min_{l,j} q(l, c + j*512) ),  c in [0,512), j in {0,1}
//   q(l,f) = max(|A[b,l,0]-B[0,f]|, |A[b,l,1]-B[1,f]|)
//   bump(t) = e/(1+e)^2, e = exp(-10 t)
// (math verified absmax==0 in R1/R2)
//
// One block per batch, thread = c owning BOTH paired f columns with a single
// min accumulator (min over j commutes with min over l). A[b] is wave-uniform
// -> scalar loads (SGPRs), so the inner loop is pure VALU: 7 ops per (l,c).
__global__ __launch_bounds__(512)
void chebbump_kernel(const float* __restrict__ A,
                     const float* __restrict__ B,
                     float* __restrict__ out)
{
    const int b = blockIdx.x;
    const int c = threadIdx.x;   // c in [0, 512)

    const float* __restrict__ Ab = A + (size_t)b * (MAXLEN * 2);

    // This thread's two B columns (f = c and f = c + 512).
    const float b0c = B[c];
    const float b1c = B[LENF + c];
    const float b0d = B[c + MAXLEN];
    const float b1d = B[LENF + MAXLEN + c];

    // 4 independent min chains over l; A reads are uniform -> s_load.
    float u0 = 3.4e38f, u1 = 3.4e38f, u2 = 3.4e38f, u3 = 3.4e38f;
#pragma unroll 4
    for (int l = 0; l < MAXLEN; l += 4) {
        const float a00 = Ab[2 * l + 0], a10 = Ab[2 * l + 1];
        const float a01 = Ab[2 * l + 2], a11 = Ab[2 * l + 3];
        const float a02 = Ab[2 * l + 4], a12 = Ab[2 * l + 5];
        const float a03 = Ab[2 * l + 6], a13 = Ab[2 * l + 7];
        u0 = fminf(u0, fminf(fmaxf(fabsf(a00 - b0c), fabsf(a10 - b1c)),
                             fmaxf(fabsf(a00 - b0d), fabsf(a10 - b1d))));
        u1 = fminf(u1, fminf(fmaxf(fabsf(a01 - b0c), fabsf(a11 - b1c)),
                             fmaxf(fabsf(a01 - b0d), fabsf(a11 - b1d))));
        u2 = fminf(u2, fminf(fmaxf(fabsf(a02 - b0c), fabsf(a12 - b1c)),
                             fmaxf(fabsf(a02 - b0d), fabsf(a12 - b1d))));
        u3 = fminf(u3, fminf(fmaxf(fabsf(a03 - b0c), fabsf(a13 - b1c)),
                             fmaxf(fabsf(a03 - b0d), fabsf(a13 - b1d))));
    }
    float v = fminf(fminf(u0, u1), fminf(u2, u3));

    // Block-wide max over the 512 c values.
    __shared__ float sw[8];
#pragma unroll
    for (int off = 32; off > 0; off >>= 1)
        v = fmaxf(v, __shfl_xor(v, off));   // 64-lane wave butterfly
    if ((c & 63) == 0) sw[c >> 6] = v;
    __syncthreads();

    if (c == 0) {
        float t = sw[0];
#pragma unroll
        for (int i = 1; i < 8; ++i) t = fmaxf(t, sw[i]);
        const float e = expf(-10.0f * t);   // t >= 0, e <= 1: stable
        const float d = 1.0f + e;
        out[b] = e / (d * d);               // sigmoid(10t)*sigmoid(-10t)
    }
}

extern "C" void kernel_launch(void* const* d_in, const int* in_sizes, int n_in,
                              void* d_out, int out_size, void* d_ws, size_t ws_size,
                              hipStream_t stream)
{
    const float* A = (const float*)d_in[0];
    const float* B = (const float*)d_in[1];
    float* out = (float*)d_out;

    hipLaunchKernelGGL(chebbump_kernel, dim3(BATCH), dim3(512), 0, stream,
                       A, B, out);
}